// Round 7
// baseline (136.844 us; speedup 1.0000x reference)
//
#include <hip/hip_runtime.h>
#include <math.h>

// Problem: B=1, L=256, D=256, H=8, DK=32, R=2
// Algebraic collapse of the reference:
//   baseX[j,d] = ({LN(q),k,v} @ W^T + b)[j,d]
//   e_ij = exp(-|t_i - t_j|)
//   score[h,i,j] = (1 + e_ij^2) * s_qk[h,j] / sqrt(32),
//     s_qk[h,j] = sum_dk baseQ[j,h*32+dk]*baseK[j,h*32+dk]
//   attn = softmax_j(score)                      (output #2)
//   ctx[i,h*32+dk] = sum_j attn[h,i,j]*(1+e_ij)*baseV[j,h*32+dk]
//   out = ctx @ fc_w^T + fc_b + q                (output #1)
// R7: attn + fc fused per-block WITHOUT atomics: each block owns 4 full
// i-rows across ALL heads, so ctx rows are complete in LDS and fc is a
// plain per-wave dot-product stream over fc_wT (transposed in proj kernel).

#define INV_TEMP 0.17677669529663687f  // 1/sqrt(32)

// ---- GEMM body: 32x32 tile, full-panel LDS, wave-split-K (as R5) ----
// mode 0: LN(X) then GEMM, store transposed [o][j]   (Q path)
// mode 1: GEMM, store transposed [o][j]              (K path)
// mode 2: GEMM, store natural [j][o]                 (V path)
__device__ __forceinline__ void gemm_panel(
    const float* __restrict__ X, const float* __restrict__ W,
    const float* __restrict__ bias, const float* __restrict__ ln_g,
    const float* __restrict__ ln_b, float* __restrict__ out, const int mode) {
  __shared__ float As[256][36];      // k-major As[k][j]; 144B rows (9x16B)
  __shared__ float Bs[256][36];
  __shared__ float Red[4][32][36];   // per-wave partials
  const int t = threadIdx.x;
  const int j0 = blockIdx.y << 5, o0 = blockIdx.x << 5;
  const int lr = t >> 3;             // panel row 0..31
  const int cg = (t & 7) << 2;       // col offset within 32-chunk
  float4 xa[8], wb[8];
#pragma unroll
  for (int u = 0; u < 8; ++u) {      // 16 loads all in flight -> one latency
    xa[u] = *(const float4*)(X + ((j0 + lr) << 8) + (u << 5) + cg);
    wb[u] = *(const float4*)(W + ((o0 + lr) << 8) + (u << 5) + cg);
  }
  if (mode == 0) {  // row LayerNorm across the 8 lanes sharing row lr
    float s = 0.f, s2 = 0.f;
#pragma unroll
    for (int u = 0; u < 8; ++u) {
      s  += xa[u].x + xa[u].y + xa[u].z + xa[u].w;
      s2 += xa[u].x * xa[u].x + xa[u].y * xa[u].y +
            xa[u].z * xa[u].z + xa[u].w * xa[u].w;
    }
#pragma unroll
    for (int off = 1; off < 8; off <<= 1) {
      s  += __shfl_xor(s, off);
      s2 += __shfl_xor(s2, off);
    }
    const float mu = s * 0.00390625f;
    const float rs = rsqrtf(s2 * 0.00390625f - mu * mu + 1e-6f);
#pragma unroll
    for (int u = 0; u < 8; ++u) {
      const float4 gv = *(const float4*)(ln_g + (u << 5) + cg);
      const float4 bv = *(const float4*)(ln_b + (u << 5) + cg);
      xa[u].x = (xa[u].x - mu) * rs * gv.x + bv.x;
      xa[u].y = (xa[u].y - mu) * rs * gv.y + bv.y;
      xa[u].z = (xa[u].z - mu) * rs * gv.z + bv.z;
      xa[u].w = (xa[u].w - mu) * rs * gv.w + bv.w;
    }
  }
#pragma unroll
  for (int u = 0; u < 8; ++u) {  // transpose-stage (~4-way banks, cheap)
    const int c = (u << 5) + cg;
    As[c + 0][lr] = xa[u].x; As[c + 1][lr] = xa[u].y;
    As[c + 2][lr] = xa[u].z; As[c + 3][lr] = xa[u].w;
    Bs[c + 0][lr] = wb[u].x; Bs[c + 1][lr] = wb[u].y;
    Bs[c + 2][lr] = wb[u].z; Bs[c + 3][lr] = wb[u].w;
  }
  __syncthreads();

  const int w = t >> 6, lane = t & 63;
  const int jb = (lane >> 3) << 2;   // 4-row group within tile
  const int ob = (lane & 7) << 2;    // 4-col group within tile
  const int kbase = w << 6;
  float acc[4][4] = {{0.f}};
#pragma unroll 8
  for (int kk = 0; kk < 64; ++kk) {
    const float4 av = *(const float4*)&As[kbase + kk][jb];
    const float4 bv = *(const float4*)&Bs[kbase + kk][ob];
    acc[0][0] = fmaf(av.x, bv.x, acc[0][0]);
    acc[0][1] = fmaf(av.x, bv.y, acc[0][1]);
    acc[0][2] = fmaf(av.x, bv.z, acc[0][2]);
    acc[0][3] = fmaf(av.x, bv.w, acc[0][3]);
    acc[1][0] = fmaf(av.y, bv.x, acc[1][0]);
    acc[1][1] = fmaf(av.y, bv.y, acc[1][1]);
    acc[1][2] = fmaf(av.y, bv.z, acc[1][2]);
    acc[1][3] = fmaf(av.y, bv.w, acc[1][3]);
    acc[2][0] = fmaf(av.z, bv.x, acc[2][0]);
    acc[2][1] = fmaf(av.z, bv.y, acc[2][1]);
    acc[2][2] = fmaf(av.z, bv.z, acc[2][2]);
    acc[2][3] = fmaf(av.z, bv.w, acc[2][3]);
    acc[3][0] = fmaf(av.w, bv.x, acc[3][0]);
    acc[3][1] = fmaf(av.w, bv.y, acc[3][1]);
    acc[3][2] = fmaf(av.w, bv.z, acc[3][2]);
    acc[3][3] = fmaf(av.w, bv.w, acc[3][3]);
  }
#pragma unroll
  for (int r = 0; r < 4; ++r)
    *(float4*)&Red[w][jb + r][ob] =
        make_float4(acc[r][0], acc[r][1], acc[r][2], acc[r][3]);
  __syncthreads();

  // final: thread t -> row j = t>>3, col-quad o4 = (t&7)*4
  const int j = t >> 3, o4 = (t & 7) << 2;
  const float4 s0 = *(const float4*)&Red[0][j][o4];
  const float4 s1 = *(const float4*)&Red[1][j][o4];
  const float4 s2 = *(const float4*)&Red[2][j][o4];
  const float4 s3 = *(const float4*)&Red[3][j][o4];
  const float4 bv4 = *(const float4*)(bias + o0 + o4);
  float4 rs4;
  rs4.x = (s0.x + s1.x) + (s2.x + s3.x) + bv4.x;
  rs4.y = (s0.y + s1.y) + (s2.y + s3.y) + bv4.y;
  rs4.z = (s0.z + s1.z) + (s2.z + s3.z) + bv4.z;
  rs4.w = (s0.w + s1.w) + (s2.w + s3.w) + bv4.w;
  const int gj = j0 + j, go = o0 + o4;
  if (mode <= 1) {  // transposed store out[o][j]
    out[((go + 0) << 8) + gj] = rs4.x;
    out[((go + 1) << 8) + gj] = rs4.y;
    out[((go + 2) << 8) + gj] = rs4.z;
    out[((go + 3) << 8) + gj] = rs4.w;
  } else {
    *(float4*)(out + (gj << 8) + go) = rs4;
  }
}

// K1: LN + 3 projection GEMMs; also transposes fc_w -> fc_wT for the fused
// fc stream (lane-coalesced reads).
__global__ __launch_bounds__(256) void mha_proj_gemm3(
    const float* __restrict__ q, const float* __restrict__ kin,
    const float* __restrict__ vin, const float* __restrict__ Wq,
    const float* __restrict__ bq, const float* __restrict__ Wk,
    const float* __restrict__ bk, const float* __restrict__ Wv,
    const float* __restrict__ bv, const float* __restrict__ ln_g,
    const float* __restrict__ ln_b, const float* __restrict__ fc_w,
    float* __restrict__ baseQT, float* __restrict__ baseKT,
    float* __restrict__ baseV, float* __restrict__ fc_wT) {
  const int z = blockIdx.z;
  const int gid = ((z << 6) + (blockIdx.y << 3) + blockIdx.x) * 256 +
                  threadIdx.x;                  // 0..49151
  {                                             // fc_w[o][d] -> fc_wT[d][o]
    const int e = gid << 1;                     // 2 elements per thread
    if (e < 65536) {
      const float2 v = *(const float2*)(fc_w + e);
      const int o = e >> 8, d = e & 255;
      fc_wT[(d << 8) + o] = v.x;
      fc_wT[((d + 1 < 256 ? d + 1 : d - 255) << 8) +
            (d + 1 < 256 ? o : o + 1)] = v.y;   // handles row wrap
    }
  }
  if (z == 0)
    gemm_panel(q, Wq, bq, ln_g, ln_b, baseQT, 0);
  else if (z == 1)
    gemm_panel(kin, Wk, bk, nullptr, nullptr, baseKT, 1);
  else
    gemm_panel(vin, Wv, bv, nullptr, nullptr, baseV, 2);
}

// K2: fused s_qk + softmax + attn output + ctx + fc (+bias+residual).
// grid 64 blocks x 256 thr (4 waves). Block owns 4 i-rows, ALL heads;
// wave w owns row i0+w end-to-end -> no atomics, no inter-wave sync for fc.
__global__ __launch_bounds__(256) void mha_attn_fc(
    const float* __restrict__ baseQT, const float* __restrict__ baseKT,
    const float* __restrict__ baseV, const float* __restrict__ tt,
    const float* __restrict__ fc_wT, const float* __restrict__ fc_b,
    const float* __restrict__ qres, float* __restrict__ attn_out,
    float* __restrict__ out) {
  const int i0 = blockIdx.x << 2;
  const int t = threadIdx.x;
  __shared__ float s_lds[8][256];    // s_qk[h][j] * invtemp
  __shared__ float P[4][256];        // per-wave attn*(1+e), reused per h
  __shared__ float ctx_lds[4][256];  // per-wave full ctx row

  // Phase A: s_qk for all heads; thread t covers j=t for h=0..7
#pragma unroll
  for (int h = 0; h < 8; ++h) {
    const float* qc = baseQT + (h << 13) + t;  // coalesced in t
    const float* kc = baseKT + (h << 13) + t;
    float acc = 0.f;
#pragma unroll
    for (int dk = 0; dk < 32; ++dk)
      acc = fmaf(qc[dk << 8], kc[dk << 8], acc);
    s_lds[h][t] = acc * INV_TEMP;
  }
  __syncthreads();

  // Phase B: per-wave row i; e-factors computed once (h-independent)
  const int w = t >> 6, lane = t & 63;
  const int i = i0 + w;
  const float ti = tt[i];
  const float4 tj = ((const float4*)tt)[lane];
  const float e0 = __expf(-fabsf(ti - tj.x));
  const float e1 = __expf(-fabsf(ti - tj.y));
  const float e2 = __expf(-fabsf(ti - tj.z));
  const float e3 = __expf(-fabsf(ti - tj.w));
  const float f0 = 1.f + e0, f1 = 1.f + e1, f2 = 1.f + e2, f3 = 1.f + e3;
  const float g0 = 1.f + e0 * e0, g1 = 1.f + e1 * e1;
  const float g2 = 1.f + e2 * e2, g3 = 1.f + e3 * e3;
  const int dk = lane & 31, half = lane >> 5;

  for (int h = 0; h < 8; ++h) {
    const float4 sv = ((const float4*)s_lds[h])[lane];
    const float sc0 = g0 * sv.x, sc1 = g1 * sv.y;
    const float sc2 = g2 * sv.z, sc3 = g3 * sv.w;
    float m = fmaxf(fmaxf(sc0, sc1), fmaxf(sc2, sc3));
#pragma unroll
    for (int off = 32; off; off >>= 1) m = fmaxf(m, __shfl_xor(m, off));
    float p0 = __expf(sc0 - m), p1 = __expf(sc1 - m);
    float p2 = __expf(sc2 - m), p3 = __expf(sc3 - m);
    float s = p0 + p1 + p2 + p3;
#pragma unroll
    for (int off = 32; off; off >>= 1) s += __shfl_xor(s, off);
    const float rinv = 1.f / s;
    p0 *= rinv; p1 *= rinv; p2 *= rinv; p3 *= rinv;
    ((float4*)(attn_out + (((h << 8) + i) << 8)))[lane] =
        make_float4(p0, p1, p2, p3);
    ((float4*)P[w])[lane] =
        make_float4(p0 * f0, p1 * f1, p2 * f2, p3 * f3);
    // same-wave LDS RAW: in-order LDS pipe + compiler lgkmcnt (R5-validated)
    const float* Pr = P[w] + (half << 7);
    const float* Vp = baseV + (h << 5) + dk + (half << 15);
    float a0 = 0.f, a1 = 0.f, a2 = 0.f, a3 = 0.f;
#pragma unroll 4
    for (int jj = 0; jj < 128; jj += 4) {
      a0 = fmaf(Pr[jj + 0], Vp[(jj + 0) << 8], a0);
      a1 = fmaf(Pr[jj + 1], Vp[(jj + 1) << 8], a1);
      a2 = fmaf(Pr[jj + 2], Vp[(jj + 2) << 8], a2);
      a3 = fmaf(Pr[jj + 3], Vp[(jj + 3) << 8], a3);
    }
    float acc = (a0 + a1) + (a2 + a3);
    acc += __shfl_xor(acc, 32);
    if (half == 0) ctx_lds[w][(h << 5) + dk] = acc;
  }

  // Phase C: fc for row i (wave-private ctx row -> no barrier needed).
  // out[i,oq..] = fc_b + q_res + sum_d ctx[d] * fc_wT[d][oq..]
  const int oq = lane << 2;
  const float4 bb = *(const float4*)(fc_b + oq);
  const float4 rr = *(const float4*)(qres + (i << 8) + oq);
  float4 acc4 = make_float4(bb.x + rr.x, bb.y + rr.y, bb.z + rr.z, bb.w + rr.w);
#pragma unroll 4
  for (int d = 0; d < 256; ++d) {
    const float c = ctx_lds[w][d];                       // wave broadcast
    const float4 w4 = *(const float4*)(fc_wT + (d << 8) + oq);  // coalesced
    acc4.x = fmaf(c, w4.x, acc4.x);
    acc4.y = fmaf(c, w4.y, acc4.y);
    acc4.z = fmaf(c, w4.z, acc4.z);
    acc4.w = fmaf(c, w4.w, acc4.w);
  }
  *(float4*)(out + (i << 8) + oq) = acc4;
}

extern "C" void kernel_launch(void* const* d_in, const int* in_sizes, int n_in,
                              void* d_out, int out_size, void* d_ws,
                              size_t ws_size, hipStream_t stream) {
  const float* q    = (const float*)d_in[0];
  const float* kin  = (const float*)d_in[1];
  const float* vin  = (const float*)d_in[2];
  const float* tt   = (const float*)d_in[3];
  const float* Wq   = (const float*)d_in[4];
  const float* bq   = (const float*)d_in[5];
  const float* Wk   = (const float*)d_in[6];
  const float* bk   = (const float*)d_in[7];
  const float* Wv   = (const float*)d_in[8];
  const float* bv   = (const float*)d_in[9];
  const float* fc_w = (const float*)d_in[10];
  const float* fc_b = (const float*)d_in[11];
  const float* ln_g = (const float*)d_in[12];
  const float* ln_b = (const float*)d_in[13];

  float* out  = (float*)d_out;   // [256,256]
  float* attn = out + 65536;     // [8,256,256]

  float* ws     = (float*)d_ws;
  float* baseQT = ws;            // [256][256] transposed [d][j]
  float* baseKT = ws + 65536;
  float* baseV  = ws + 131072;   // natural [j][d]
  float* fc_wT  = ws + 196608;   // [d][o]

  hipLaunchKernelGGL(mha_proj_gemm3, dim3(8, 8, 3), dim3(256), 0, stream, q,
                     kin, vin, Wq, bq, Wk, bk, Wv, bv, ln_g, ln_b, fc_w,
                     baseQT, baseKT, baseV, fc_wT);
  hipLaunchKernelGGL(mha_attn_fc, dim3(64), dim3(256), 0, stream, baseQT,
                     baseKT, baseV, tt, fc_wT, fc_b, q, attn, out);
}

// Round 9
// 100.445 us; speedup vs baseline: 1.3624x; 1.3624x over previous
//
#include <hip/hip_runtime.h>
#include <math.h>

// Problem: B=1, L=256, D=256, H=8, DK=32, R=2
// Algebraic collapse of the reference:
//   baseX[j,d] = ({LN(q),k,v} @ W^T + b)[j,d]
//   e_ij = exp(-|t_i - t_j|)
//   score[h,i,j] = (1 + e_ij^2) * s_qk[h,j] / sqrt(32),
//     s_qk[h,j] = sum_dk baseQ[j,h*32+dk]*baseK[j,h*32+dk]
//   attn = softmax_j(score)                      (output #2)
//   ctx[i,h*32+dk] = sum_j attn[h,i,j]*(1+e_ij)*baseV[j,h*32+dk]
//   out = ctx @ fc_w^T + fc_b + q                (output #1)
// R8 = R5 structure (best measured, 96.5us) + V stored transposed so the
// attn PV loop is float4 along j (4x fewer VMEM instrs), + phase-A s_qk
// split across all 8 waves. No fusion of fc (R6 atomics and R7 low-occupancy
// fusions both regressed).

#define INV_TEMP 0.17677669529663687f  // 1/sqrt(32)

// ---- GEMM body: 32x32 tile, full-panel LDS, wave-split-K ----
// 256 thr = 4 waves; wave w owns K-slice [w*64, w*64+64); lane = 8x8 grid,
// each lane a 4x4 micro-tile via two ds_read_b128 per k (pad 36 -> 16B-
// aligned, conflict-free reads). Partials reduced across waves through LDS.
// mode 0: LN(X) then GEMM, store transposed [o][j]   (Q path)
// mode 1: GEMM, store transposed [o][j]              (K and V paths)
// mode 3: GEMM, natural + bias + residual            (fc path)
__device__ __forceinline__ void gemm_panel(
    const float* __restrict__ X, const float* __restrict__ W,
    const float* __restrict__ bias, const float* __restrict__ res,
    const float* __restrict__ ln_g, const float* __restrict__ ln_b,
    float* __restrict__ out, const int mode) {
  __shared__ float As[256][36];      // k-major As[k][j]; 144B rows (9x16B)
  __shared__ float Bs[256][36];
  __shared__ float Red[4][32][36];   // per-wave partials
  const int t = threadIdx.x;
  const int j0 = blockIdx.y << 5, o0 = blockIdx.x << 5;
  const int lr = t >> 3;             // panel row 0..31
  const int cg = (t & 7) << 2;       // col offset within 32-chunk
  float4 xa[8], wb[8];
#pragma unroll
  for (int u = 0; u < 8; ++u) {      // 16 loads all in flight -> one latency
    xa[u] = *(const float4*)(X + ((j0 + lr) << 8) + (u << 5) + cg);
    wb[u] = *(const float4*)(W + ((o0 + lr) << 8) + (u << 5) + cg);
  }
  if (mode == 0) {  // row LayerNorm across the 8 lanes sharing row lr
    float s = 0.f, s2 = 0.f;
#pragma unroll
    for (int u = 0; u < 8; ++u) {
      s  += xa[u].x + xa[u].y + xa[u].z + xa[u].w;
      s2 += xa[u].x * xa[u].x + xa[u].y * xa[u].y +
            xa[u].z * xa[u].z + xa[u].w * xa[u].w;
    }
#pragma unroll
    for (int off = 1; off < 8; off <<= 1) {
      s  += __shfl_xor(s, off);
      s2 += __shfl_xor(s2, off);
    }
    const float mu = s * 0.00390625f;
    const float rs = rsqrtf(s2 * 0.00390625f - mu * mu + 1e-6f);
#pragma unroll
    for (int u = 0; u < 8; ++u) {
      const float4 gv = *(const float4*)(ln_g + (u << 5) + cg);
      const float4 bv = *(const float4*)(ln_b + (u << 5) + cg);
      xa[u].x = (xa[u].x - mu) * rs * gv.x + bv.x;
      xa[u].y = (xa[u].y - mu) * rs * gv.y + bv.y;
      xa[u].z = (xa[u].z - mu) * rs * gv.z + bv.z;
      xa[u].w = (xa[u].w - mu) * rs * gv.w + bv.w;
    }
  }
#pragma unroll
  for (int u = 0; u < 8; ++u) {  // transpose-stage (~4-way banks, cheap)
    const int c = (u << 5) + cg;
    As[c + 0][lr] = xa[u].x; As[c + 1][lr] = xa[u].y;
    As[c + 2][lr] = xa[u].z; As[c + 3][lr] = xa[u].w;
    Bs[c + 0][lr] = wb[u].x; Bs[c + 1][lr] = wb[u].y;
    Bs[c + 2][lr] = wb[u].z; Bs[c + 3][lr] = wb[u].w;
  }
  __syncthreads();

  const int w = t >> 6, lane = t & 63;
  const int jb = (lane >> 3) << 2;   // 4-row group within tile
  const int ob = (lane & 7) << 2;    // 4-col group within tile
  const int kbase = w << 6;
  float acc[4][4] = {{0.f}};
#pragma unroll 8
  for (int kk = 0; kk < 64; ++kk) {
    const float4 av = *(const float4*)&As[kbase + kk][jb];
    const float4 bv = *(const float4*)&Bs[kbase + kk][ob];
    acc[0][0] = fmaf(av.x, bv.x, acc[0][0]);
    acc[0][1] = fmaf(av.x, bv.y, acc[0][1]);
    acc[0][2] = fmaf(av.x, bv.z, acc[0][2]);
    acc[0][3] = fmaf(av.x, bv.w, acc[0][3]);
    acc[1][0] = fmaf(av.y, bv.x, acc[1][0]);
    acc[1][1] = fmaf(av.y, bv.y, acc[1][1]);
    acc[1][2] = fmaf(av.y, bv.z, acc[1][2]);
    acc[1][3] = fmaf(av.y, bv.w, acc[1][3]);
    acc[2][0] = fmaf(av.z, bv.x, acc[2][0]);
    acc[2][1] = fmaf(av.z, bv.y, acc[2][1]);
    acc[2][2] = fmaf(av.z, bv.z, acc[2][2]);
    acc[2][3] = fmaf(av.z, bv.w, acc[2][3]);
    acc[3][0] = fmaf(av.w, bv.x, acc[3][0]);
    acc[3][1] = fmaf(av.w, bv.y, acc[3][1]);
    acc[3][2] = fmaf(av.w, bv.z, acc[3][2]);
    acc[3][3] = fmaf(av.w, bv.w, acc[3][3]);
  }
#pragma unroll
  for (int r = 0; r < 4; ++r)
    *(float4*)&Red[w][jb + r][ob] =
        make_float4(acc[r][0], acc[r][1], acc[r][2], acc[r][3]);
  __syncthreads();

  // final: thread t -> row j = t>>3, col-quad o4 = (t&7)*4
  const int j = t >> 3, o4 = (t & 7) << 2;
  const float4 s0 = *(const float4*)&Red[0][j][o4];
  const float4 s1 = *(const float4*)&Red[1][j][o4];
  const float4 s2 = *(const float4*)&Red[2][j][o4];
  const float4 s3 = *(const float4*)&Red[3][j][o4];
  const float4 bv4 = *(const float4*)(bias + o0 + o4);
  float4 rs4;
  rs4.x = (s0.x + s1.x) + (s2.x + s3.x) + bv4.x;
  rs4.y = (s0.y + s1.y) + (s2.y + s3.y) + bv4.y;
  rs4.z = (s0.z + s1.z) + (s2.z + s3.z) + bv4.z;
  rs4.w = (s0.w + s1.w) + (s2.w + s3.w) + bv4.w;
  const int gj = j0 + j, go = o0 + o4;
  if (mode <= 1) {  // transposed store out[o][j]
    out[((go + 0) << 8) + gj] = rs4.x;
    out[((go + 1) << 8) + gj] = rs4.y;
    out[((go + 2) << 8) + gj] = rs4.z;
    out[((go + 3) << 8) + gj] = rs4.w;
  } else {
    if (mode == 3) {
      const float4 rv = *(const float4*)(res + (gj << 8) + go);
      rs4.x += rv.x; rs4.y += rv.y; rs4.z += rv.z; rs4.w += rv.w;
    }
    *(float4*)(out + (gj << 8) + go) = rs4;
  }
}

// K1: LN + 3 projection GEMMs, one dispatch (grid.z = q/k/v).
// Q, K, V all stored transposed [d][j] for coalesced/vectorized attn reads.
__global__ __launch_bounds__(256) void mha_proj_gemm3(
    const float* __restrict__ q, const float* __restrict__ kin,
    const float* __restrict__ vin, const float* __restrict__ Wq,
    const float* __restrict__ bq, const float* __restrict__ Wk,
    const float* __restrict__ bk, const float* __restrict__ Wv,
    const float* __restrict__ bv, const float* __restrict__ ln_g,
    const float* __restrict__ ln_b, float* __restrict__ baseQT,
    float* __restrict__ baseKT, float* __restrict__ baseVT) {
  const int z = blockIdx.z;
  if (z == 0)
    gemm_panel(q, Wq, bq, nullptr, ln_g, ln_b, baseQT, 0);
  else if (z == 1)
    gemm_panel(kin, Wk, bk, nullptr, nullptr, nullptr, baseKT, 1);
  else
    gemm_panel(vin, Wv, bv, nullptr, nullptr, nullptr, baseVT, 1);
}

// K3: fc GEMM + bias + residual
__global__ __launch_bounds__(256) void mha_fc_gemm(
    const float* __restrict__ ctxf, const float* __restrict__ fc_w,
    const float* __restrict__ fc_b, const float* __restrict__ q,
    float* __restrict__ out) {
  gemm_panel(ctxf, fc_w, fc_b, q, nullptr, nullptr, out, 3);
}

// K2: fused s_qk + softmax + attn output + ctx
// grid (32, 8): blockIdx.y = head, blockIdx.x = 8-row i-tile; 512 thr = 8 waves
__global__ __launch_bounds__(512) void mha_attn_fused(
    const float* __restrict__ baseQT, const float* __restrict__ baseKT,
    const float* __restrict__ baseVT, const float* __restrict__ tt,
    float* __restrict__ attn_out, float* __restrict__ ctxf) {
  const int h = blockIdx.y;
  const int i0 = blockIdx.x << 3;
  const int t = threadIdx.x;
  __shared__ float s_part[2][256];  // s_qk partials (dk halves) * invtemp
  __shared__ float P[8][256];       // per-wave attn*(1+e)
  // Phase A: all 512 threads; thread (j=t&255, dh=t>>8) does 16 dk terms
  {
    const int j = t & 255, dh = t >> 8;
    const float* qc = baseQT + (((h << 5) + (dh << 4)) << 8) + j;
    const float* kc = baseKT + (((h << 5) + (dh << 4)) << 8) + j;
    float acc = 0.f;
#pragma unroll
    for (int r = 0; r < 16; ++r)
      acc = fmaf(qc[r << 8], kc[r << 8], acc);
    s_part[dh][j] = acc * INV_TEMP;
  }
  __syncthreads();

  const int w = t >> 6, lane = t & 63;
  const int i = i0 + w;
  const float ti = tt[i];
  const float4 tj = ((const float4*)tt)[lane];
  const float4 sa = ((const float4*)s_part[0])[lane];
  const float4 sb = ((const float4*)s_part[1])[lane];
  const float4 sv = make_float4(sa.x + sb.x, sa.y + sb.y,
                                sa.z + sb.z, sa.w + sb.w);
  const float e0 = __expf(-fabsf(ti - tj.x));
  const float e1 = __expf(-fabsf(ti - tj.y));
  const float e2 = __expf(-fabsf(ti - tj.z));
  const float e3 = __expf(-fabsf(ti - tj.w));
  const float sc0 = (1.f + e0 * e0) * sv.x;
  const float sc1 = (1.f + e1 * e1) * sv.y;
  const float sc2 = (1.f + e2 * e2) * sv.z;
  const float sc3 = (1.f + e3 * e3) * sv.w;
  float m = fmaxf(fmaxf(sc0, sc1), fmaxf(sc2, sc3));
#pragma unroll
  for (int off = 32; off; off >>= 1) m = fmaxf(m, __shfl_xor(m, off));
  float p0 = __expf(sc0 - m), p1 = __expf(sc1 - m);
  float p2 = __expf(sc2 - m), p3 = __expf(sc3 - m);
  float s = p0 + p1 + p2 + p3;
#pragma unroll
  for (int off = 32; off; off >>= 1) s += __shfl_xor(s, off);
  const float rinv = 1.f / s;
  p0 *= rinv; p1 *= rinv; p2 *= rinv; p3 *= rinv;
  ((float4*)(attn_out + (((h << 8) + i) << 8)))[lane] =
      make_float4(p0, p1, p2, p3);
  ((float4*)P[w])[lane] = make_float4(p0 * (1.f + e0), p1 * (1.f + e1),
                                      p2 * (1.f + e2), p3 * (1.f + e3));

  // ctx[i, h*32+dk] = sum_j P[j] * VT[h*32+dk][j]; j-halves per lane-half.
  // float4 along j: 32 VMEM loads + 32 LDS broadcast reads per lane.
  const int dk = lane & 31, half = lane >> 5;
  const float* Pr = P[w] + (half << 7);                     // LDS, broadcast
  const float* Vp = baseVT + (((h << 5) + dk) << 8) + (half << 7);
  float4 a4 = make_float4(0.f, 0.f, 0.f, 0.f);
#pragma unroll 8
  for (int jj = 0; jj < 128; jj += 4) {
    const float4 pv = *(const float4*)(Pr + jj);
    const float4 vv = *(const float4*)(Vp + jj);
    a4.x = fmaf(pv.x, vv.x, a4.x);
    a4.y = fmaf(pv.y, vv.y, a4.y);
    a4.z = fmaf(pv.z, vv.z, a4.z);
    a4.w = fmaf(pv.w, vv.w, a4.w);
  }
  float acc = (a4.x + a4.y) + (a4.z + a4.w);
  acc += __shfl_xor(acc, 32);
  if (half == 0) ctxf[(i << 8) + (h << 5) + dk] = acc;
}

extern "C" void kernel_launch(void* const* d_in, const int* in_sizes, int n_in,
                              void* d_out, int out_size, void* d_ws,
                              size_t ws_size, hipStream_t stream) {
  const float* q    = (const float*)d_in[0];
  const float* kin  = (const float*)d_in[1];
  const float* vin  = (const float*)d_in[2];
  const float* tt   = (const float*)d_in[3];
  const float* Wq   = (const float*)d_in[4];
  const float* bq   = (const float*)d_in[5];
  const float* Wk   = (const float*)d_in[6];
  const float* bk   = (const float*)d_in[7];
  const float* Wv   = (const float*)d_in[8];
  const float* bv   = (const float*)d_in[9];
  const float* fc_w = (const float*)d_in[10];
  const float* fc_b = (const float*)d_in[11];
  const float* ln_g = (const float*)d_in[12];
  const float* ln_b = (const float*)d_in[13];

  float* out  = (float*)d_out;   // [256,256]
  float* attn = out + 65536;     // [8,256,256]

  float* ws     = (float*)d_ws;
  float* baseQT = ws;            // [256][256] transposed [d][j]
  float* baseKT = ws + 65536;
  float* baseVT = ws + 131072;   // transposed [d][j]
  float* ctxf   = ws + 196608;   // [i][h*32+dk]

  hipLaunchKernelGGL(mha_proj_gemm3, dim3(8, 8, 3), dim3(256), 0, stream, q,
                     kin, vin, Wq, bq, Wk, bk, Wv, bv, ln_g, ln_b, baseQT,
                     baseKT, baseVT);
  hipLaunchKernelGGL(mha_attn_fused, dim3(32, 8), dim3(512), 0, stream,
                     baseQT, baseKT, baseVT, tt, attn, ctxf);
  hipLaunchKernelGGL(mha_fc_gemm, dim3(8, 8), dim3(256), 0, stream, ctxf,
                     fc_w, fc_b, q, out);
}

// Round 10
// 97.976 us; speedup vs baseline: 1.3967x; 1.0252x over previous
//
#include <hip/hip_runtime.h>
#include <math.h>

// Problem: B=1, L=256, D=256, H=8, DK=32, R=2
// Algebraic collapse of the reference:
//   baseX[j,d] = ({LN(q),k,v} @ W^T + b)[j,d]
//   e_ij = exp(-|t_i - t_j|)
//   score[h,i,j] = (1 + e_ij^2) * s_qk[h,j] / sqrt(32),
//     s_qk[h,j] = sum_dk baseQ[j,h*32+dk]*baseK[j,h*32+dk]
//   attn = softmax_j(score)                      (output #2)
//   ctx[i,h*32+dk] = sum_j attn[h,i,j]*(1+e_ij)*baseV[j,h*32+dk]
//   out = ctx @ fc_w^T + fc_b + q                (output #1)
// R10 = R5 exact (measured best, 96.5us: V natural, scalar coalesced PV)
// + ONLY the phase-A 8-wave s_qk split (isolated change; R9's V-transpose
// gather regression reverted).

#define INV_TEMP 0.17677669529663687f  // 1/sqrt(32)

// ---- GEMM body: 32x32 tile, full-panel LDS, wave-split-K ----
// 256 thr = 4 waves; wave w owns K-slice [w*64, w*64+64); lane = 8x8 grid,
// each lane a 4x4 micro-tile via two ds_read_b128 per k (pad 36 -> 16B-
// aligned, conflict-free reads). Partials reduced across waves through LDS.
// mode 0: LN(X) then GEMM, store transposed [o][j]   (Q path)
// mode 1: GEMM, store transposed [o][j]              (K path)
// mode 2: GEMM, store natural [j][o]                 (V path)
// mode 3: GEMM, natural + bias + residual            (fc path)
__device__ __forceinline__ void gemm_panel(
    const float* __restrict__ X, const float* __restrict__ W,
    const float* __restrict__ bias, const float* __restrict__ res,
    const float* __restrict__ ln_g, const float* __restrict__ ln_b,
    float* __restrict__ out, const int mode) {
  __shared__ float As[256][36];      // k-major As[k][j]; 144B rows (9x16B)
  __shared__ float Bs[256][36];
  __shared__ float Red[4][32][36];   // per-wave partials
  const int t = threadIdx.x;
  const int j0 = blockIdx.y << 5, o0 = blockIdx.x << 5;
  const int lr = t >> 3;             // panel row 0..31
  const int cg = (t & 7) << 2;       // col offset within 32-chunk
  float4 xa[8], wb[8];
#pragma unroll
  for (int u = 0; u < 8; ++u) {      // 16 loads all in flight -> one latency
    xa[u] = *(const float4*)(X + ((j0 + lr) << 8) + (u << 5) + cg);
    wb[u] = *(const float4*)(W + ((o0 + lr) << 8) + (u << 5) + cg);
  }
  if (mode == 0) {  // row LayerNorm across the 8 lanes sharing row lr
    float s = 0.f, s2 = 0.f;
#pragma unroll
    for (int u = 0; u < 8; ++u) {
      s  += xa[u].x + xa[u].y + xa[u].z + xa[u].w;
      s2 += xa[u].x * xa[u].x + xa[u].y * xa[u].y +
            xa[u].z * xa[u].z + xa[u].w * xa[u].w;
    }
#pragma unroll
    for (int off = 1; off < 8; off <<= 1) {
      s  += __shfl_xor(s, off);
      s2 += __shfl_xor(s2, off);
    }
    const float mu = s * 0.00390625f;
    const float rs = rsqrtf(s2 * 0.00390625f - mu * mu + 1e-6f);
#pragma unroll
    for (int u = 0; u < 8; ++u) {
      const float4 gv = *(const float4*)(ln_g + (u << 5) + cg);
      const float4 bv = *(const float4*)(ln_b + (u << 5) + cg);
      xa[u].x = (xa[u].x - mu) * rs * gv.x + bv.x;
      xa[u].y = (xa[u].y - mu) * rs * gv.y + bv.y;
      xa[u].z = (xa[u].z - mu) * rs * gv.z + bv.z;
      xa[u].w = (xa[u].w - mu) * rs * gv.w + bv.w;
    }
  }
#pragma unroll
  for (int u = 0; u < 8; ++u) {  // transpose-stage (~4-way banks, cheap)
    const int c = (u << 5) + cg;
    As[c + 0][lr] = xa[u].x; As[c + 1][lr] = xa[u].y;
    As[c + 2][lr] = xa[u].z; As[c + 3][lr] = xa[u].w;
    Bs[c + 0][lr] = wb[u].x; Bs[c + 1][lr] = wb[u].y;
    Bs[c + 2][lr] = wb[u].z; Bs[c + 3][lr] = wb[u].w;
  }
  __syncthreads();

  const int w = t >> 6, lane = t & 63;
  const int jb = (lane >> 3) << 2;   // 4-row group within tile
  const int ob = (lane & 7) << 2;    // 4-col group within tile
  const int kbase = w << 6;
  float acc[4][4] = {{0.f}};
#pragma unroll 8
  for (int kk = 0; kk < 64; ++kk) {
    const float4 av = *(const float4*)&As[kbase + kk][jb];
    const float4 bv = *(const float4*)&Bs[kbase + kk][ob];
    acc[0][0] = fmaf(av.x, bv.x, acc[0][0]);
    acc[0][1] = fmaf(av.x, bv.y, acc[0][1]);
    acc[0][2] = fmaf(av.x, bv.z, acc[0][2]);
    acc[0][3] = fmaf(av.x, bv.w, acc[0][3]);
    acc[1][0] = fmaf(av.y, bv.x, acc[1][0]);
    acc[1][1] = fmaf(av.y, bv.y, acc[1][1]);
    acc[1][2] = fmaf(av.y, bv.z, acc[1][2]);
    acc[1][3] = fmaf(av.y, bv.w, acc[1][3]);
    acc[2][0] = fmaf(av.z, bv.x, acc[2][0]);
    acc[2][1] = fmaf(av.z, bv.y, acc[2][1]);
    acc[2][2] = fmaf(av.z, bv.z, acc[2][2]);
    acc[2][3] = fmaf(av.z, bv.w, acc[2][3]);
    acc[3][0] = fmaf(av.w, bv.x, acc[3][0]);
    acc[3][1] = fmaf(av.w, bv.y, acc[3][1]);
    acc[3][2] = fmaf(av.w, bv.z, acc[3][2]);
    acc[3][3] = fmaf(av.w, bv.w, acc[3][3]);
  }
#pragma unroll
  for (int r = 0; r < 4; ++r)
    *(float4*)&Red[w][jb + r][ob] =
        make_float4(acc[r][0], acc[r][1], acc[r][2], acc[r][3]);
  __syncthreads();

  // final: thread t -> row j = t>>3, col-quad o4 = (t&7)*4
  const int j = t >> 3, o4 = (t & 7) << 2;
  const float4 s0 = *(const float4*)&Red[0][j][o4];
  const float4 s1 = *(const float4*)&Red[1][j][o4];
  const float4 s2 = *(const float4*)&Red[2][j][o4];
  const float4 s3 = *(const float4*)&Red[3][j][o4];
  const float4 bv4 = *(const float4*)(bias + o0 + o4);
  float4 rs4;
  rs4.x = (s0.x + s1.x) + (s2.x + s3.x) + bv4.x;
  rs4.y = (s0.y + s1.y) + (s2.y + s3.y) + bv4.y;
  rs4.z = (s0.z + s1.z) + (s2.z + s3.z) + bv4.z;
  rs4.w = (s0.w + s1.w) + (s2.w + s3.w) + bv4.w;
  const int gj = j0 + j, go = o0 + o4;
  if (mode <= 1) {  // transposed store out[o][j]
    out[((go + 0) << 8) + gj] = rs4.x;
    out[((go + 1) << 8) + gj] = rs4.y;
    out[((go + 2) << 8) + gj] = rs4.z;
    out[((go + 3) << 8) + gj] = rs4.w;
  } else {
    if (mode == 3) {
      const float4 rv = *(const float4*)(res + (gj << 8) + go);
      rs4.x += rv.x; rs4.y += rv.y; rs4.z += rv.z; rs4.w += rv.w;
    }
    *(float4*)(out + (gj << 8) + go) = rs4;
  }
}

// K1: LN + 3 projection GEMMs, one dispatch (grid.z = q/k/v)
__global__ __launch_bounds__(256) void mha_proj_gemm3(
    const float* __restrict__ q, const float* __restrict__ kin,
    const float* __restrict__ vin, const float* __restrict__ Wq,
    const float* __restrict__ bq, const float* __restrict__ Wk,
    const float* __restrict__ bk, const float* __restrict__ Wv,
    const float* __restrict__ bv, const float* __restrict__ ln_g,
    const float* __restrict__ ln_b, float* __restrict__ baseQT,
    float* __restrict__ baseKT, float* __restrict__ baseV) {
  const int z = blockIdx.z;
  if (z == 0)
    gemm_panel(q, Wq, bq, nullptr, ln_g, ln_b, baseQT, 0);
  else if (z == 1)
    gemm_panel(kin, Wk, bk, nullptr, nullptr, nullptr, baseKT, 1);
  else
    gemm_panel(vin, Wv, bv, nullptr, nullptr, nullptr, baseV, 2);
}

// K3: fc GEMM + bias + residual
__global__ __launch_bounds__(256) void mha_fc_gemm(
    const float* __restrict__ ctxf, const float* __restrict__ fc_w,
    const float* __restrict__ fc_b, const float* __restrict__ q,
    float* __restrict__ out) {
  gemm_panel(ctxf, fc_w, fc_b, q, nullptr, nullptr, out, 3);
}

// K2: fused s_qk + softmax + attn output + ctx
// grid (32, 8): blockIdx.y = head, blockIdx.x = 8-row i-tile; 512 thr = 8 waves
__global__ __launch_bounds__(512) void mha_attn_fused(
    const float* __restrict__ baseQT, const float* __restrict__ baseKT,
    const float* __restrict__ baseV, const float* __restrict__ tt,
    float* __restrict__ attn_out, float* __restrict__ ctxf) {
  const int h = blockIdx.y;
  const int i0 = blockIdx.x << 3;
  const int t = threadIdx.x;
  __shared__ float s_part[2][256];  // s_qk partials (dk halves) * invtemp
  __shared__ float P[8][256];       // per-wave attn*(1+e)
  // Phase A: all 512 threads; thread (j=t&255, dh=t>>8) does 16 dk terms
  {
    const int j = t & 255, dh = t >> 8;
    const float* qc = baseQT + (((h << 5) + (dh << 4)) << 8) + j;
    const float* kc = baseKT + (((h << 5) + (dh << 4)) << 8) + j;
    float acc = 0.f;
#pragma unroll
    for (int r = 0; r < 16; ++r)
      acc = fmaf(qc[r << 8], kc[r << 8], acc);
    s_part[dh][j] = acc * INV_TEMP;
  }
  __syncthreads();

  const int w = t >> 6, lane = t & 63;
  const int i = i0 + w;
  const float ti = tt[i];
  const float4 tj = ((const float4*)tt)[lane];
  const float4 sa = ((const float4*)s_part[0])[lane];
  const float4 sb = ((const float4*)s_part[1])[lane];
  const float4 sv = make_float4(sa.x + sb.x, sa.y + sb.y,
                                sa.z + sb.z, sa.w + sb.w);
  const float e0 = __expf(-fabsf(ti - tj.x));
  const float e1 = __expf(-fabsf(ti - tj.y));
  const float e2 = __expf(-fabsf(ti - tj.z));
  const float e3 = __expf(-fabsf(ti - tj.w));
  const float sc0 = (1.f + e0 * e0) * sv.x;
  const float sc1 = (1.f + e1 * e1) * sv.y;
  const float sc2 = (1.f + e2 * e2) * sv.z;
  const float sc3 = (1.f + e3 * e3) * sv.w;
  float m = fmaxf(fmaxf(sc0, sc1), fmaxf(sc2, sc3));
#pragma unroll
  for (int off = 32; off; off >>= 1) m = fmaxf(m, __shfl_xor(m, off));
  float p0 = __expf(sc0 - m), p1 = __expf(sc1 - m);
  float p2 = __expf(sc2 - m), p3 = __expf(sc3 - m);
  float s = p0 + p1 + p2 + p3;
#pragma unroll
  for (int off = 32; off; off >>= 1) s += __shfl_xor(s, off);
  const float rinv = 1.f / s;
  p0 *= rinv; p1 *= rinv; p2 *= rinv; p3 *= rinv;
  ((float4*)(attn_out + (((h << 8) + i) << 8)))[lane] =
      make_float4(p0, p1, p2, p3);
  ((float4*)P[w])[lane] = make_float4(p0 * (1.f + e0), p1 * (1.f + e1),
                                      p2 * (1.f + e2), p3 * (1.f + e3));

  // ctx[i, h*32+dk] = sum_j P[j] * baseV[j][h*32+dk]; halves of j per
  // lane-half. Scalar loads: per instruction each half-wave reads a 128B
  // contiguous segment (measured-good R5 pattern; do NOT transpose V).
  const int dk = lane & 31, half = lane >> 5;
  const float* Pr = P[w] + (half << 7);
  const float* Vp = baseV + (h << 5) + dk + (half << 15);
  float a0 = 0.f, a1 = 0.f, a2 = 0.f, a3 = 0.f;
#pragma unroll 4
  for (int jj = 0; jj < 128; jj += 4) {
    a0 = fmaf(Pr[jj + 0], Vp[(jj + 0) << 8], a0);
    a1 = fmaf(Pr[jj + 1], Vp[(jj + 1) << 8], a1);
    a2 = fmaf(Pr[jj + 2], Vp[(jj + 2) << 8], a2);
    a3 = fmaf(Pr[jj + 3], Vp[(jj + 3) << 8], a3);
  }
  float acc = (a0 + a1) + (a2 + a3);
  acc += __shfl_xor(acc, 32);
  if (half == 0) ctxf[(i << 8) + (h << 5) + dk] = acc;
}

extern "C" void kernel_launch(void* const* d_in, const int* in_sizes, int n_in,
                              void* d_out, int out_size, void* d_ws,
                              size_t ws_size, hipStream_t stream) {
  const float* q    = (const float*)d_in[0];
  const float* kin  = (const float*)d_in[1];
  const float* vin  = (const float*)d_in[2];
  const float* tt   = (const float*)d_in[3];
  const float* Wq   = (const float*)d_in[4];
  const float* bq   = (const float*)d_in[5];
  const float* Wk   = (const float*)d_in[6];
  const float* bk   = (const float*)d_in[7];
  const float* Wv   = (const float*)d_in[8];
  const float* bv   = (const float*)d_in[9];
  const float* fc_w = (const float*)d_in[10];
  const float* fc_b = (const float*)d_in[11];
  const float* ln_g = (const float*)d_in[12];
  const float* ln_b = (const float*)d_in[13];

  float* out  = (float*)d_out;   // [256,256]
  float* attn = out + 65536;     // [8,256,256]

  float* ws     = (float*)d_ws;
  float* baseQT = ws;            // [256][256] transposed [d][j]
  float* baseKT = ws + 65536;
  float* baseV  = ws + 131072;   // natural [j][d]
  float* ctxf   = ws + 196608;   // [i][h*32+dk]

  hipLaunchKernelGGL(mha_proj_gemm3, dim3(8, 8, 3), dim3(256), 0, stream, q,
                     kin, vin, Wq, bq, Wk, bk, Wv, bv, ln_g, ln_b, baseQT,
                     baseKT, baseV);
  hipLaunchKernelGGL(mha_attn_fused, dim3(32, 8), dim3(512), 0, stream,
                     baseQT, baseKT, baseV, tt, attn, ctxf);
  hipLaunchKernelGGL(mha_fc_gemm, dim3(8, 8), dim3(256), 0, stream, ctxf,
                     fc_w, fc_b, q, out);
}